// Round 10
// baseline (243.613 us; speedup 1.0000x reference)
//
#include <hip/hip_runtime.h>

// Delta scan with residual carry, one thread per row (65536 rows x 512 f32).
//
// Ladder: R6 direct strided stores = 2.31x write amp -> R7 LDS transpose
// stores (131 MB ideal) -> R8 barrier-free wave-private tiles (87 us) ->
// R9 depth-2 reg prefetch (83 us; VGPR=168 shows compiler still collapses
// register pipelines; 2.46 TB/s, latency-starved at 1 wave/SIMD).
//
// R10: data plane moved to LDS via global_load_lds DMA (no VGPR round
// trip -> nothing to sink). Per wave, per 32-float chunk: 8 fire-and-
// forget DMA (per-lane gather: lane = row; linear LDS dest [f4slot][lane]),
// ring of 3 input tiles, prefetch distance 2, ONE counted s_waitcnt
// vmcnt(16) per iter (never 0). Count proof: iter = [8 DMA][wait][scan]
// [8 st]; at the wait the 16 newest VMEM ops are DMA(c+2)+St(c-1), so
// <=16 outstanding => DMA(c) landed. Holds for prologue (c=0: 24
// outstanding -> oldest 8 = DMA(0) drained) and tail. Zero barriers:
// all tiles wave-private, DS pipe in-order per wave (validated R8/R9).
// LDS: 4 waves x (3 x 8 KB in + 8 KB out) = 128 KB, 1 block/CU.

#define T_LEN 512

constexpr int BLOCK  = 256;
constexpr int WAVE   = 64;
constexpr int CF4    = 8;                      // float4 per chunk per row (32 floats)
constexpr int RPF4   = T_LEN / 4;              // 128 f4 per row
constexpr int NCHUNK = RPF4 / CF4;             // 16 chunks
constexpr int RING   = 3;
constexpr int NWAVE  = BLOCK / WAVE;

__global__ __launch_bounds__(BLOCK, 1) void delta_scan_kernel(
    const float* __restrict__ x,
    const float* __restrict__ thrp,
    float* __restrict__ out)
{
    // input tiles: layout [f4slot k][lane] per tile -- matches DMA's
    // (uniform base + lane*16B) dest rule. out tile: row-major XOR-swizzled.
    __shared__ float4 in_t[NWAVE][RING][CF4 * WAVE];   // 96 KB
    __shared__ float4 out_t[NWAVE][WAVE * CF4];        // 32 KB

    const int tid  = threadIdx.x;
    const int wid  = tid >> 6;
    const int lane = tid & 63;

    const int row   = blockIdx.x * BLOCK + tid;        // this lane's row
    const int wrow0 = blockIdx.x * BLOCK + wid * WAVE; // wave's first row

    const float thr = fmaxf(thrp[0], 0.015625f);

    const float4* __restrict__ xv = reinterpret_cast<const float4*>(x);
    float4* __restrict__       ov = reinterpret_cast<float4*>(out);
    const size_t rb = (size_t)row * RPF4;              // my row base (f4 units)

    float4* const ot = out_t[wid];

    // ---- DMA stage: chunk cc -> in_t[wid][cc%RING]; instruction k writes
    // lane's 16B (f4 #(cc*CF4+k) of lane's row) at slot base + lane*16.
#define STAGE(cc)                                                         \
    {                                                                     \
        float4* dst = in_t[wid][(cc) % RING];                             \
        _Pragma("unroll")                                                 \
        for (int k = 0; k < CF4; ++k)                                     \
            __builtin_amdgcn_global_load_lds(                             \
                (const void*)&xv[rb + (size_t)(cc) * CF4 + k],            \
                (void*)&dst[k * WAVE], 16, 0, 0);                         \
    }

    // prologue: chunks 0,1 in flight
    STAGE(0)
    STAGE(1)

    float pre = 0.0f, res = 0.0f;

#pragma unroll
    for (int c = 0; c < NCHUNK; ++c) {
        if (c + 2 < NCHUNK) STAGE(c + 2)

        // counted wait: DMA(c) landed; DMA(c+2)+St(c-1) may stay in flight
        asm volatile("s_waitcnt vmcnt(16)" ::: "memory");

        // scan chunk c from in tile, deposit swizzled into out tile
        const float4* src = in_t[wid][c % RING];
#pragma unroll
        for (int i = 0; i < CF4; ++i) {
            const float4 v = src[i * WAVE + lane];   // ds_read_b128, 16B/lane
            float4 q;
            // exact reference op order: d=(x-pre)+res; y=|d|>=thr?d:0;
            // res=d-y (==big?0:d bit-exact); out=floor(y*64)*2^-6 (exact)
            { float d=(v.x-pre)+res; bool b=fabsf(d)>=thr; float y=b?d:0.0f;
              res=b?0.0f:d; pre=v.x; q.x=floorf(y*64.0f)*0.015625f; }
            { float d=(v.y-pre)+res; bool b=fabsf(d)>=thr; float y=b?d:0.0f;
              res=b?0.0f:d; pre=v.y; q.y=floorf(y*64.0f)*0.015625f; }
            { float d=(v.z-pre)+res; bool b=fabsf(d)>=thr; float y=b?d:0.0f;
              res=b?0.0f:d; pre=v.z; q.z=floorf(y*64.0f)*0.015625f; }
            { float d=(v.w-pre)+res; bool b=fabsf(d)>=thr; float y=b?d:0.0f;
              res=b?0.0f:d; pre=v.w; q.w=floorf(y*64.0f)*0.015625f; }

            ot[lane * CF4 + (i ^ (lane & 7))] = q;
        }

        // store-out chunk c: 8 rounds; each 8-lane group stores one full
        // 128B line (row rr, f4 jj). WAR vs next iter's ds_writes is safe:
        // DS pipe is in-order per wave (R8/R9, absmax=0).
#pragma unroll
        for (int k = 0; k < CF4; ++k) {
            const int rr = k * 8 + (lane >> 3);
            const int jj = lane & 7;
            const float4 t4 = ot[rr * CF4 + (jj ^ (rr & 7))];
            ov[(size_t)(wrow0 + rr) * RPF4 + c * CF4 + jj] = t4;
        }
    }
#undef STAGE
}

extern "C" void kernel_launch(void* const* d_in, const int* in_sizes, int n_in,
                              void* d_out, int out_size, void* d_ws, size_t ws_size,
                              hipStream_t stream)
{
    const float* x    = (const float*)d_in[0];
    const float* thrp = (const float*)d_in[1];
    float*       out  = (float*)d_out;

    const int rows = in_sizes[0] / T_LEN;   // 65536
    const int grid = rows / BLOCK;          // 256 blocks, 1 per CU

    delta_scan_kernel<<<grid, BLOCK, 0, stream>>>(x, thrp, out);
}